// Round 1
// baseline (911.567 us; speedup 1.0000x reference)
//
#include <hip/hip_runtime.h>
#include <cstdint>

typedef __bf16 bf16;
typedef bf16 bf16x4 __attribute__((ext_vector_type(4)));
typedef bf16 bf16x8 __attribute__((ext_vector_type(8)));
typedef float f32x4 __attribute__((ext_vector_type(4)));

// ---------------------------------------------------------------------------
// K1a: vertical 12-tap FIR, stride 2 vertically. taps tv[j] = f2d[j][0]
// in : hm  [8,32,512,512] f32
// out: v   [8,32,256,512] bf16   (scaled by f1[0] -- compensated in K1b)
// ---------------------------------------------------------------------------
__global__ __launch_bounds__(256) void k1_vert(const float* __restrict__ hm,
                                               const float* __restrict__ f2d,
                                               bf16* __restrict__ v) {
    int o = blockIdx.x * 256 + threadIdx.x;   // 33,554,432 total
    int xi = o & 511;
    int yy = (o >> 9) & 255;
    int bc = o >> 17;
    const float* src = hm + (size_t)bc * 262144 + xi;
    int rbase = 2 * yy - 5;
    float acc = 0.f;
#pragma unroll
    for (int j = 0; j < 12; ++j) {
        int r = rbase + j;
        float tap = f2d[j * 12];              // f1[j]*f1[0]
        if ((unsigned)r < 512u) acc += tap * src[r * 512];
    }
    v[o] = (bf16)acc;
}

// ---------------------------------------------------------------------------
// K1b: horizontal 12-tap FIR, stride 2, taps th[i] = f2d[0][i]/f2d[0][0]
// (tv[j]*th[i] == f2d[j][i] to ~1e-7), + transpose-pack to NHWC bf16.
// in : v   [8,32,256,512] bf16
// out: hmd [524288 pixels][32 ch] bf16   (pixel = (b*256+y)*256+x)
// one block per (b,y): 256 threads = 256 x-positions
// ---------------------------------------------------------------------------
__global__ __launch_bounds__(256) void k1_horiz(const bf16* __restrict__ v,
                                                const float* __restrict__ f2d,
                                                bf16* __restrict__ hmd) {
    __shared__ bf16 T[32 * 257];
    int by = blockIdx.x;          // b*256 + y
    int t = threadIdx.x;          // x
    int b = by >> 8, y = by & 255;
    float inv = 1.0f / f2d[0];
    float th[12];
#pragma unroll
    for (int i = 0; i < 12; ++i) th[i] = f2d[i] * inv;
#pragma unroll 1
    for (int c = 0; c < 32; ++c) {
        const bf16* row = v + (size_t)((b * 32 + c) * 256 + y) * 512;
        float acc = 0.f;
        int cb = 2 * t - 5;
#pragma unroll
        for (int i = 0; i < 12; ++i) {
            int cc = cb + i;
            if ((unsigned)cc < 512u) acc += th[i] * (float)row[cc];
        }
        T[c * 257 + t] = (bf16)acc;
    }
    __syncthreads();
    const unsigned short* Ts = (const unsigned short*)T;
    unsigned int u[16];
#pragma unroll
    for (int g = 0; g < 16; ++g) {
        unsigned int lo = Ts[(2 * g) * 257 + t];
        unsigned int hi = Ts[(2 * g + 1) * 257 + t];
        u[g] = lo | (hi << 16);
    }
    size_t p = (size_t)by * 256 + t;
    uint4* dst = (uint4*)(hmd + p * 32);
    dst[0] = make_uint4(u[0], u[1], u[2], u[3]);
    dst[1] = make_uint4(u[4], u[5], u[6], u[7]);
    dst[2] = make_uint4(u[8], u[9], u[10], u[11]);
    dst[3] = make_uint4(u[12], u[13], u[14], u[15]);
}

// ---------------------------------------------------------------------------
// K0: weights -> bf16.  wsb[n][k] n<128,k<32 ; wcat[n][k] n<128,k<128
// (rows contiguous in k == exact B-fragment layout for 16x16x32 mfma)
// ---------------------------------------------------------------------------
__global__ __launch_bounds__(256) void k0_prep(const float* __restrict__ w_shared,
                                               const float* __restrict__ w_gamma,
                                               const float* __restrict__ w_beta,
                                               bf16* __restrict__ wsb,
                                               bf16* __restrict__ wcat) {
    int t = blockIdx.x * 256 + threadIdx.x;   // 16384 total
    if (t < 4096) wsb[t] = (bf16)w_shared[t];
    int n = t >> 7, k = t & 127;
    float wv = (n < 64) ? w_gamma[n * 128 + k] : w_beta[(n - 64) * 128 + k];
    wcat[t] = (bf16)wv;
}

// ---------------------------------------------------------------------------
// K2: InstanceNorm stats. one block per (b,c); 65536 elems.
// ---------------------------------------------------------------------------
__global__ __launch_bounds__(256) void k2_stats(const float* __restrict__ x,
                                                float* __restrict__ meanp,
                                                float* __restrict__ rstdp) {
    int bc = blockIdx.x;
    const float* p = x + (size_t)bc * 65536;
    int tid = threadIdx.x;
    float s = 0.f, s2 = 0.f;
#pragma unroll 4
    for (int i = 0; i < 64; ++i) {
        f32x4 vv = *(const f32x4*)(p + (i * 256 + tid) * 4);
        s += vv[0] + vv[1] + vv[2] + vv[3];
        s2 += vv[0] * vv[0] + vv[1] * vv[1] + vv[2] * vv[2] + vv[3] * vv[3];
    }
#pragma unroll
    for (int off = 32; off > 0; off >>= 1) {
        s += __shfl_down(s, off);
        s2 += __shfl_down(s2, off);
    }
    __shared__ float red[8];
    int w = tid >> 6, lane = tid & 63;
    if (lane == 0) { red[w] = s; red[4 + w] = s2; }
    __syncthreads();
    if (tid == 0) {
        float S = red[0] + red[1] + red[2] + red[3];
        float S2 = red[4] + red[5] + red[6] + red[7];
        float mu = S * (1.f / 65536.f);
        float var = S2 * (1.f / 65536.f) - mu * mu;
        meanp[bc] = mu;
        rstdp[bc] = rsqrtf(var + 1e-5f);
    }
}

// ---------------------------------------------------------------------------
// K3: fused  h = lrelu(U*Ws^T + bs)*sqrt2 ; [gamma|beta] = h*Wcat^T + bias ;
//            out = (x-mu)*rstd*(1+gamma) + beta + 0.1*x
// block = 128 contiguous pixels (same b,y). 4 waves x 32 pixels.
// 16x16x32 bf16 MFMA.  A-frag: m=lane&15, k=quad*8+j.  D: n=lane&15, m=quad*4+r.
// ---------------------------------------------------------------------------
__global__ __launch_bounds__(256) void k3_fused(
    const bf16* __restrict__ hmd, const bf16* __restrict__ wsb,
    const bf16* __restrict__ wcat, const float* __restrict__ bsh,
    const float* __restrict__ bga, const float* __restrict__ bbe,
    const float* __restrict__ x, const float* __restrict__ meanp,
    const float* __restrict__ rstdp, float* __restrict__ out) {
    constexpr int HROW = 136;                 // bf16 units; 272B rows, 16B-aligned frags
    __shared__ bf16 buf[4 * 4608];            // per-wave: H[32][136] then GB[128][36]
    __shared__ float smean[64], srstd[64];

    const int tid = threadIdx.x;
    const int w = tid >> 6;
    const int lane = tid & 63;
    const int l15 = lane & 15;
    const int quad = lane >> 4;

    const int bid = blockIdx.x;               // 4096 blocks
    const int b = bid >> 9;
    const int y = (bid >> 1) & 255;
    const int x0 = (bid & 1) << 7;

    if (tid < 64) {
        smean[tid] = meanp[b * 64 + tid];
        srstd[tid] = rstdp[b * 64 + tid];
    }

    bf16* Hw = buf + w * 4608;
    const int pw = bid * 128 + w * 32;        // wave's pixel base

    // ---- GEMM1: K=32, one MFMA per (mt,nt) tile ----
    bf16x8 a1[2];
#pragma unroll
    for (int mt = 0; mt < 2; ++mt)
        a1[mt] = *(const bf16x8*)(hmd + (size_t)(pw + mt * 16 + l15) * 32 + quad * 8);
    bf16x8 b1[8];
#pragma unroll
    for (int nt = 0; nt < 8; ++nt)
        b1[nt] = *(const bf16x8*)(wsb + (nt * 16 + l15) * 32 + quad * 8);
    f32x4 zero4 = {0.f, 0.f, 0.f, 0.f};
    f32x4 acc[2][8];
#pragma unroll
    for (int mt = 0; mt < 2; ++mt)
#pragma unroll
        for (int nt = 0; nt < 8; ++nt)
            acc[mt][nt] = __builtin_amdgcn_mfma_f32_16x16x32_bf16(a1[mt], b1[nt], zero4, 0, 0, 0);

    // bias + lrelu*sqrt2 -> H in LDS (C-frag -> A-frag layout transform)
#pragma unroll
    for (int nt = 0; nt < 8; ++nt) {
        float bs = bsh[nt * 16 + l15];
#pragma unroll
        for (int mt = 0; mt < 2; ++mt) {
#pragma unroll
            for (int r = 0; r < 4; ++r) {
                float hv = acc[mt][nt][r] + bs;
                hv = (hv >= 0.f ? hv : 0.2f * hv) * 1.41421356237309515f;
                int m = mt * 16 + quad * 4 + r;
                Hw[m * HROW + nt * 16 + l15] = (bf16)hv;
            }
        }
    }

    // ---- GEMM2: K=128 over 4 kt steps ----
    f32x4 acc2[2][8];
#pragma unroll
    for (int mt = 0; mt < 2; ++mt)
#pragma unroll
        for (int nt = 0; nt < 8; ++nt) acc2[mt][nt] = zero4;
#pragma unroll 1
    for (int kt = 0; kt < 4; ++kt) {
        bf16x8 b2[8];
#pragma unroll
        for (int nt = 0; nt < 8; ++nt)
            b2[nt] = *(const bf16x8*)(wcat + (nt * 16 + l15) * 128 + kt * 32 + quad * 8);
        bf16x8 a2[2];
#pragma unroll
        for (int mt = 0; mt < 2; ++mt)
            a2[mt] = *(const bf16x8*)(Hw + (mt * 16 + l15) * HROW + kt * 32 + quad * 8);
#pragma unroll
        for (int mt = 0; mt < 2; ++mt)
#pragma unroll
            for (int nt = 0; nt < 8; ++nt)
                acc2[mt][nt] = __builtin_amdgcn_mfma_f32_16x16x32_bf16(a2[mt], b2[nt], acc2[mt][nt], 0, 0, 0);
    }

    // gamma/beta (+bias) -> LDS bf16, layout GB[c][px_in_wave], row stride 36
    // (overwrites H region of this wave -- H is dead; same-wave DS ordering)
#pragma unroll
    for (int nt = 0; nt < 8; ++nt) {
        int n = nt * 16 + l15;
        float bias = (n < 64) ? bga[n] : bbe[n - 64];
#pragma unroll
        for (int mt = 0; mt < 2; ++mt) {
            bf16x4 pk;
#pragma unroll
            for (int r = 0; r < 4; ++r) pk[r] = (bf16)(acc2[mt][nt][r] + bias);
            int m0 = mt * 16 + quad * 4;
            *(bf16x4*)(Hw + n * 36 + m0) = pk;
        }
    }
    __syncthreads();

    // ---- epilogue: InstanceNorm + FiLM + skip ----
    const size_t xbase = (size_t)b * 64 * 65536 + (size_t)y * 256 + x0;
#pragma unroll
    for (int it = 0; it < 8; ++it) {
        int g = it * 256 + tid;
        int c = g >> 5;                       // 0..63
        int px = (g & 31) * 4;                // 0..124
        int wv = px >> 5, pm = px & 31;
        const bf16* GBv = buf + wv * 4608;
        bf16x4 gg = *(const bf16x4*)(GBv + c * 36 + pm);
        bf16x4 bb = *(const bf16x4*)(GBv + (c + 64) * 36 + pm);
        f32x4 xv = *(const f32x4*)(x + xbase + (size_t)c * 65536 + px);
        float mu = smean[c], rs = srstd[c];
        f32x4 o;
#pragma unroll
        for (int r = 0; r < 4; ++r) {
            float xn = (xv[r] - mu) * rs;
            o[r] = xn * (1.f + (float)gg[r]) + (float)bb[r] + 0.1f * xv[r];
        }
        *(f32x4*)(out + xbase + (size_t)c * 65536 + px) = o;
    }
}

// ---------------------------------------------------------------------------
extern "C" void kernel_launch(void* const* d_in, const int* in_sizes, int n_in,
                              void* d_out, int out_size, void* d_ws, size_t ws_size,
                              hipStream_t stream) {
    const float* x        = (const float*)d_in[0];
    const float* hm       = (const float*)d_in[1];
    const float* f2d      = (const float*)d_in[2];
    const float* w_shared = (const float*)d_in[3];
    const float* b_shared = (const float*)d_in[4];
    const float* w_gamma  = (const float*)d_in[5];
    const float* b_gamma  = (const float*)d_in[6];
    const float* w_beta   = (const float*)d_in[7];
    const float* b_beta   = (const float*)d_in[8];
    float* out = (float*)d_out;
    char* ws = (char*)d_ws;

    bf16*  v     = (bf16*)(ws + 0);             // 67,108,864 B
    bf16*  hmd   = (bf16*)(ws + 67108864);      // 33,554,432 B
    bf16*  wsb   = (bf16*)(ws + 100663296);     // 8,192 B
    bf16*  wcat  = (bf16*)(ws + 100671488);     // 32,768 B
    float* meanp = (float*)(ws + 100704256);    // 2,048 B
    float* rstdp = (float*)(ws + 100706304);    // 2,048 B

    hipLaunchKernelGGL(k1_vert,  dim3(131072), dim3(256), 0, stream, hm, f2d, v);
    hipLaunchKernelGGL(k1_horiz, dim3(2048),   dim3(256), 0, stream, v, f2d, hmd);
    hipLaunchKernelGGL(k0_prep,  dim3(64),     dim3(256), 0, stream, w_shared, w_gamma, w_beta, wsb, wcat);
    hipLaunchKernelGGL(k2_stats, dim3(512),    dim3(256), 0, stream, x, meanp, rstdp);
    hipLaunchKernelGGL(k3_fused, dim3(4096),   dim3(256), 0, stream,
                       hmd, wsb, wcat, b_shared, b_gamma, b_beta, x, meanp, rstdp, out);
}